// Round 3
// baseline (183.156 us; speedup 1.0000x reference)
//
#include <hip/hip_runtime.h>
#include <hip/hip_bf16.h>

// B=64, T=128, D=512. gates = x @ w_ih^T per t; f-gate unused (c0=0).
// Kernel 0: split x (fp32) -> interleaved bf16 hi/lo (RN) groups in d_ws.
// Kernel 1: bf16x3-split MFMA GEMM (32x32x16, i/g/o rows only) + LSTM act -> h.
// Kernel 2: in-place softmax(20*h).

#define B_ 64
#define T_ 128
#define D_ 512

typedef float f32x16_t __attribute__((ext_vector_type(16)));
typedef __bf16 bf16x8_t __attribute__((ext_vector_type(8)));
typedef unsigned short u16x8_t __attribute__((ext_vector_type(8)));

// Round-to-nearest split: f = hi + lo + O(2^-18 |f|). ~3 VALU/elem.
__device__ __forceinline__ void cvt8(float4 a, float4 b, u16x8_t& hi, u16x8_t& lo) {
  float f[8] = {a.x, a.y, a.z, a.w, b.x, b.y, b.z, b.w};
#pragma unroll
  for (int j = 0; j < 8; ++j) {
    __bf16 h = (__bf16)f[j];
    hi[j] = __builtin_bit_cast(unsigned short, h);
    float r = f[j] - (float)h;
    __bf16 l = (__bf16)r;
    lo[j] = __builtin_bit_cast(unsigned short, l);
  }
}

__device__ __forceinline__ f32x16_t mfma32(u16x8_t a, u16x8_t b, f32x16_t c) {
  return __builtin_amdgcn_mfma_f32_32x32x16_bf16(
      __builtin_bit_cast(bf16x8_t, a), __builtin_bit_cast(bf16x8_t, b), c, 0, 0, 0);
}

__device__ __forceinline__ float sigmoid_f(float v) { return 1.0f / (1.0f + __expf(-v)); }
__device__ __forceinline__ float tanh_f(float v) { return 1.0f - 2.0f / (__expf(2.0f * v) + 1.0f); }

// Kernel 0: one 8-elem group per thread. ws group j: ushorts [j*16,+8)=hi, [+8,+16)=lo.
__global__ __launch_bounds__(256) void split_x_kernel(const float* __restrict__ x,
                                                      unsigned short* __restrict__ ws) {
  const int j = blockIdx.x * 256 + threadIdx.x;
  float4 a = *(const float4*)(x + (size_t)j * 8);
  float4 b = *(const float4*)(x + (size_t)j * 8 + 4);
  u16x8_t hi, lo;
  cvt8(a, b, hi, lo);
  *(u16x8_t*)(ws + (size_t)j * 16) = hi;
  *(u16x8_t*)(ws + (size_t)j * 16 + 8) = lo;
}

// Grid: 1024 WGs = 128 t x 8 d-tiles (64 cols). Block: 4 waves, each one 32x32
// output tile per gate: wave wv -> rows (wv&1)*32.., cols d0+(wv>>1)*32...
// All 1024 blocks resident (4/CU); XCD swizzle keeps each t's 8 d-tiles on one XCD.
__global__ __launch_bounds__(256, 4) void lstm_gates_kernel(
    const unsigned short* __restrict__ xs, const float* __restrict__ w,
    float* __restrict__ hout) {
  const int lane = threadIdx.x & 63;
  const int wv = threadIdx.x >> 6;
  const int bid = blockIdx.x;
  const int work = (bid & 7) * 128 + (bid >> 3);
  const int t = work >> 3;
  const int d0 = (work & 7) << 6;

  const int c = lane & 31;   // x-row / w-col within 32x32 tile
  const int kg = lane >> 5;  // k-subgroup: elems kg*8 .. kg*8+7 of each k16 step
  const int rbase = (wv & 1) * 32;
  const int cbase = d0 + (wv >> 1) * 32;

  // x groups: (b*T+t)*64 groups of 16 ushorts; step s needs group 2s+kg.
  const unsigned short* xp = xs + ((size_t)((rbase + c) * T_ + t) << 10) + kg * 16;
  // w[t][row][k]: gate rows i(0), g(2D), o(3D); f skipped.
  const float* wp[3];
  const int gbase[3] = {0, 2 * D_, 3 * D_};
#pragma unroll
  for (int g = 0; g < 3; ++g)
    wp[g] = w + ((size_t)t << 20) + ((size_t)(gbase[g] + cbase + c) << 9) + kg * 8;

  f32x16_t acc[3];
#pragma unroll
  for (int g = 0; g < 3; ++g) acc[g] = (f32x16_t)(0.f);

#pragma unroll 2
  for (int s = 0; s < 32; ++s) {  // 32 k-steps of 16
    u16x8_t xh = *(const u16x8_t*)(xp + s * 32);
    u16x8_t xl = *(const u16x8_t*)(xp + s * 32 + 8);
#pragma unroll
    for (int g = 0; g < 3; ++g) {
      float4 a = *(const float4*)(wp[g] + s * 16);
      float4 b = *(const float4*)(wp[g] + s * 16 + 4);
      u16x8_t wh, wl;
      cvt8(a, b, wh, wl);
      acc[g] = mfma32(xh, wh, acc[g]);  // hi*hi
      acc[g] = mfma32(xh, wl, acc[g]);  // hi*lo
      acc[g] = mfma32(xl, wh, acc[g]);  // lo*hi
    }
  }

  // C layout (32x32): col = lane&31, row = (j&3) + 8*(j>>2) + 4*kg  [m74/m101]
  const int dcol = cbase + c;
#pragma unroll
  for (int j = 0; j < 16; ++j) {
    float iv = acc[0][j];
    float gv = acc[1][j];
    float ov = acc[2][j];
    float cc = sigmoid_f(iv) * tanh_f(gv);
    float h = sigmoid_f(ov) * tanh_f(cc);
    int b = rbase + (j & 3) + 8 * (j >> 2) + 4 * kg;
    hout[(((size_t)b * T_ + t) << 9) + dcol] = h;
  }
}

// One wave per (b,t) row of 512; in-place softmax(20*h).
__global__ __launch_bounds__(256) void softmax_kernel(float* __restrict__ io) {
  const int lane = threadIdx.x & 63;
  const int row = blockIdx.x * 4 + (threadIdx.x >> 6);
  float* p = io + ((size_t)row << 9);
  float4 v0 = *(const float4*)(p + lane * 4);
  float4 v1 = *(const float4*)(p + 256 + lane * 4);
  float l[8] = {20.f * v0.x, 20.f * v0.y, 20.f * v0.z, 20.f * v0.w,
                20.f * v1.x, 20.f * v1.y, 20.f * v1.z, 20.f * v1.w};
  float m = l[0];
#pragma unroll
  for (int j = 1; j < 8; ++j) m = fmaxf(m, l[j]);
#pragma unroll
  for (int o = 32; o > 0; o >>= 1) m = fmaxf(m, __shfl_xor(m, o, 64));
  float e[8], s = 0.f;
#pragma unroll
  for (int j = 0; j < 8; ++j) {
    e[j] = __expf(l[j] - m);
    s += e[j];
  }
#pragma unroll
  for (int o = 32; o > 0; o >>= 1) s += __shfl_xor(s, o, 64);
  float inv = 1.0f / s;
  float4 o0 = {e[0] * inv, e[1] * inv, e[2] * inv, e[3] * inv};
  float4 o1 = {e[4] * inv, e[5] * inv, e[6] * inv, e[7] * inv};
  *(float4*)(p + lane * 4) = o0;
  *(float4*)(p + 256 + lane * 4) = o1;
}

extern "C" void kernel_launch(void* const* d_in, const int* in_sizes, int n_in,
                              void* d_out, int out_size, void* d_ws, size_t ws_size,
                              hipStream_t stream) {
  const float* x = (const float*)d_in[0];
  const float* w = (const float*)d_in[1];
  float* out = (float*)d_out;
  unsigned short* xs = (unsigned short*)d_ws;  // 16.8 MB bf16 hi/lo groups

  split_x_kernel<<<(B_ * T_ * D_) / (256 * 8), 256, 0, stream>>>(x, xs);
  lstm_gates_kernel<<<T_ * 8, 256, 0, stream>>>(xs, w, out);
  softmax_kernel<<<(B_ * T_) / 4, 256, 0, stream>>>(out);
}

// Round 4
// 125.877 us; speedup vs baseline: 1.4550x; 1.4550x over previous
//
#include <hip/hip_runtime.h>
#include <hip/hip_bf16.h>

// B=64, T=128, D=512. gates = x @ w_ih^T per t; f-gate unused (c0=0).
// K0: split x fp32 -> interleaved bf16 hi/lo groups in d_ws.
// K1: per-(t,64-col) block; 12 substages stage 16 w-rows (32KB) each via
//     global_load_lds (sequential HBM reads) into swizzled double-buffered LDS;
//     compute phase is VMEM-free (x frags preloaded in VGPRs); bf16x3 MFMA;
//     LSTM activation fused; h -> d_out.
// K2: in-place softmax(20*h).

#define B_ 64
#define T_ 128
#define D_ 512

typedef float f32x4_t __attribute__((ext_vector_type(4)));
typedef __bf16 bf16x8_t __attribute__((ext_vector_type(8)));
typedef unsigned short u16x8_t __attribute__((ext_vector_type(8)));
typedef unsigned int u32;
typedef const __attribute__((address_space(1))) u32* gp_t;
typedef __attribute__((address_space(3))) u32* lp_t;

#define GLOAD_LDS16(g, l) \
  __builtin_amdgcn_global_load_lds((gp_t)(const void*)(g), (lp_t)(void*)(l), 16, 0, 0)

// Round-to-nearest split: f = hi + lo + O(2^-18 |f|).
__device__ __forceinline__ void cvt8(float4 a, float4 b, u16x8_t& hi, u16x8_t& lo) {
  float f[8] = {a.x, a.y, a.z, a.w, b.x, b.y, b.z, b.w};
#pragma unroll
  for (int j = 0; j < 8; ++j) {
    __bf16 h = (__bf16)f[j];
    hi[j] = __builtin_bit_cast(unsigned short, h);
    float r = f[j] - (float)h;
    __bf16 l = (__bf16)r;
    lo[j] = __builtin_bit_cast(unsigned short, l);
  }
}

__device__ __forceinline__ f32x4_t mfma16(u16x8_t a, u16x8_t b, f32x4_t c) {
  return __builtin_amdgcn_mfma_f32_16x16x32_bf16(
      __builtin_bit_cast(bf16x8_t, a), __builtin_bit_cast(bf16x8_t, b), c, 0, 0, 0);
}

__device__ __forceinline__ float sigmoid_f(float v) { return 1.0f / (1.0f + __expf(-v)); }
__device__ __forceinline__ float tanh_f(float v) { return 1.0f - 2.0f / (__expf(2.0f * v) + 1.0f); }

// K0: one 8-elem group per thread. ws group j: ushorts [j*16,+8)=hi, [+8,+16)=lo.
__global__ __launch_bounds__(256) void split_x_kernel(const float* __restrict__ x,
                                                      unsigned short* __restrict__ ws) {
  const int j = blockIdx.x * 256 + threadIdx.x;
  float4 a = *(const float4*)(x + (size_t)j * 8);
  float4 b = *(const float4*)(x + (size_t)j * 8 + 4);
  u16x8_t hi, lo;
  cvt8(a, b, hi, lo);
  *(u16x8_t*)(ws + (size_t)j * 16) = hi;
  *(u16x8_t*)(ws + (size_t)j * 16 + 8) = lo;
}

// Grid 1024 = 128 t x 8 d-tiles. 4 waves; wave wv owns b-rows [wv*16,+16).
__global__ __launch_bounds__(256, 2) void lstm_gates_kernel(
    const unsigned short* __restrict__ xs, const float* __restrict__ w,
    float* __restrict__ hout) {
  __shared__ float lds[2][8192];  // 2 x 32KB (16 w-rows of 512 fp32, XOR-swizzled)
  const int lane = threadIdx.x & 63;
  const int wv = threadIdx.x >> 6;
  const int bid = blockIdx.x;
  // XCD swizzle: the 8 d-tiles of each t share an XCD (x slice L2-resident).
  const int work = (bid & 7) * 128 + (bid >> 3);
  const int t = work >> 3;
  const int d0 = (work & 7) << 6;

  const int c = lane & 15;   // frag row/col index
  const int kg = lane >> 4;  // k-subgroup 0..3

  // ---- x A-frag preload: b-row = wv*16 + c, all K=512 as 16 steps of hi/lo u16x8.
  const unsigned short* xsb = xs + ((size_t)((wv * 16 + c) * T_ + t) << 10);
  u16x8_t xh[16], xl[16];
#pragma unroll
  for (int st = 0; st < 16; ++st) {
    xh[st] = *(const u16x8_t*)(xsb + st * 64 + kg * 16);
    xl[st] = *(const u16x8_t*)(xsb + st * 64 + kg * 16 + 8);
  }

  // ---- DMA source offsets (pre-swizzled global so linear-DMA lands swizzled).
  // LDS slot P (byte in 32KB tile) holds content linear L = P ^ ((row(P)&7)<<4).
  unsigned soff[8];
#pragma unroll
  for (int i = 0; i < 8; ++i) {
    unsigned P = (unsigned)(wv * 8192 + i * 1024 + lane * 16);
    soff[i] = P ^ (((P >> 11) & 7) << 4);
  }

  // ---- fragment read bases: lin = c*2048 + kg*32 + h*16 (+ step*128 via imm).
  const unsigned sw = (unsigned)((c & 7) << 4);
  const unsigned rb0 = ((unsigned)(c * 2048 + kg * 32)) ^ sw;
  const unsigned rb1 = ((unsigned)(c * 2048 + kg * 32 + 16)) ^ sw;

  // substage s: gate g = s>>2 (row base 0/1024/1536), col-group cg = s&3.
  const unsigned sboff[12] = {
      (0u + 0 * 16) * 2048u,    (0u + 1 * 16) * 2048u,    (0u + 2 * 16) * 2048u,    (0u + 3 * 16) * 2048u,
      (1024u + 0 * 16) * 2048u, (1024u + 1 * 16) * 2048u, (1024u + 2 * 16) * 2048u, (1024u + 3 * 16) * 2048u,
      (1536u + 0 * 16) * 2048u, (1536u + 1 * 16) * 2048u, (1536u + 2 * 16) * 2048u, (1536u + 3 * 16) * 2048u};
  const char* wbytes = (const char*)w + ((size_t)t << 22) + (size_t)d0 * 2048;

  f32x4_t acc[12];
#pragma unroll
  for (int s = 0; s < 12; ++s) acc[s] = (f32x4_t){0.f, 0.f, 0.f, 0.f};

  // ---- prologue DMA(0)
  {
    const char* gb = wbytes + sboff[0];
    char* lb = (char*)&lds[0][0] + wv * 8192;
#pragma unroll
    for (int i = 0; i < 8; ++i) GLOAD_LDS16(gb + soff[i], lb + i * 1024);
  }

#pragma unroll
  for (int s = 0; s < 12; ++s) {
    if (s < 11) {  // DMA(s+1) into the other buffer
      const char* gb = wbytes + sboff[s + 1];
      char* lb = (char*)&lds[(s + 1) & 1][0] + wv * 8192;
#pragma unroll
      for (int i = 0; i < 8; ++i) GLOAD_LDS16(gb + soff[i], lb + i * 1024);
    }
    __builtin_amdgcn_sched_barrier(0);
    if (s < 11) asm volatile("s_waitcnt vmcnt(8)" ::: "memory");  // DMA(s) retired
    else        asm volatile("s_waitcnt vmcnt(0)" ::: "memory");
    __builtin_amdgcn_s_barrier();  // buf[s&1] visible to all waves
    __builtin_amdgcn_sched_barrier(0);

    const char* lb = (const char*)&lds[s & 1][0];
#pragma unroll
    for (int st = 0; st < 16; ++st) {
      float4 wa = *(const float4*)(lb + rb0 + st * 128);
      float4 wb = *(const float4*)(lb + rb1 + st * 128);
      u16x8_t wh, wl;
      cvt8(wa, wb, wh, wl);
      acc[s] = mfma16(xh[st], wh, acc[s]);
      acc[s] = mfma16(xh[st], wl, acc[s]);
      acc[s] = mfma16(xl[st], wh, acc[s]);
    }
    __builtin_amdgcn_sched_barrier(0);
    __builtin_amdgcn_s_barrier();  // all waves done reading buf[s&1]
  }

  // ---- LSTM activation + h write. C frag: col = c, row = kg*4 + j.
#pragma unroll
  for (int cg = 0; cg < 4; ++cg) {
#pragma unroll
    for (int j = 0; j < 4; ++j) {
      float iv = acc[cg][j];
      float gv = acc[4 + cg][j];
      float ov = acc[8 + cg][j];
      float cc = sigmoid_f(iv) * tanh_f(gv);
      float h = sigmoid_f(ov) * tanh_f(cc);
      int b = wv * 16 + kg * 4 + j;
      int dcol = d0 + cg * 16 + c;
      hout[(((size_t)b * T_ + t) << 9) + dcol] = h;
    }
  }
}

// One wave per (b,t) row of 512; in-place softmax(20*h).
__global__ __launch_bounds__(256) void softmax_kernel(float* __restrict__ io) {
  const int lane = threadIdx.x & 63;
  const int row = blockIdx.x * 4 + (threadIdx.x >> 6);
  float* p = io + ((size_t)row << 9);
  float4 v0 = *(const float4*)(p + lane * 4);
  float4 v1 = *(const float4*)(p + 256 + lane * 4);
  float l[8] = {20.f * v0.x, 20.f * v0.y, 20.f * v0.z, 20.f * v0.w,
                20.f * v1.x, 20.f * v1.y, 20.f * v1.z, 20.f * v1.w};
  float m = l[0];
#pragma unroll
  for (int j = 1; j < 8; ++j) m = fmaxf(m, l[j]);
#pragma unroll
  for (int o = 32; o > 0; o >>= 1) m = fmaxf(m, __shfl_xor(m, o, 64));
  float e[8], s = 0.f;
#pragma unroll
  for (int j = 0; j < 8; ++j) {
    e[j] = __expf(l[j] - m);
    s += e[j];
  }
#pragma unroll
  for (int o = 32; o > 0; o >>= 1) s += __shfl_xor(s, o, 64);
  float inv = 1.0f / s;
  float4 o0 = {e[0] * inv, e[1] * inv, e[2] * inv, e[3] * inv};
  float4 o1 = {e[4] * inv, e[5] * inv, e[6] * inv, e[7] * inv};
  *(float4*)(p + lane * 4) = o0;
  *(float4*)(p + 256 + lane * 4) = o1;
}

extern "C" void kernel_launch(void* const* d_in, const int* in_sizes, int n_in,
                              void* d_out, int out_size, void* d_ws, size_t ws_size,
                              hipStream_t stream) {
  const float* x = (const float*)d_in[0];
  const float* w = (const float*)d_in[1];
  float* out = (float*)d_out;
  unsigned short* xs = (unsigned short*)d_ws;  // 16.8 MB bf16 hi/lo groups

  split_x_kernel<<<(B_ * T_ * D_) / (256 * 8), 256, 0, stream>>>(x, xs);
  lstm_gates_kernel<<<T_ * 8, 256, 0, stream>>>(xs, w, out);
  softmax_kernel<<<(B_ * T_) / 4, 256, 0, stream>>>(out);
}